// Round 12
// baseline (85.219 us; speedup 1.0000x reference)
//
#include <hip/hip_runtime.h>
#include <hip/hip_bf16.h>

#define NP 512                     // particles
#define DD 128                     // dims
#define NPAIRS (NP * (NP - 1) / 2) // 130816

// Hybrid bitonic sort of 512 floats (ascending): value in register r, one per
// thread; __shfl_xor for partner distance < 64, LDS exchange for s >= 64.
__device__ __forceinline__ float bitonic512(float r, int tid, float* lds)
{
    for (int k = 2; k <= NP; k <<= 1) {
        for (int s = k >> 1; s > 0; s >>= 1) {
            float other;
            if (s < 64) {
                other = __shfl_xor(r, s);
            } else {
                __syncthreads();
                lds[tid] = r;
                __syncthreads();
                other = lds[tid ^ s];
            }
            const bool lower = (tid & s) == 0;
            const bool up    = (tid & k) == 0;
            r = (lower == up) ? fminf(r, other) : fmaxf(r, other);
        }
    }
    return r;
}

// ---------------------------------------------------------------------------
// Kernel 1: per-dimension exact median of upper-triangular pairwise squared
// differences. One block (512 threads) per dimension d.
//   1) bitonic sort -> v[] (LDS); vj = v[tid]
//   2) SINGLE-WAVE Illinois rounds (wave 0 only, ZERO barriers/round):
//      lane owns 8 j's (j = lane + 64w) with warm windows [A_w,B_w] on
//      L_j(x) = first i with fl(v[j]-v[i]) <= x (monotone in i and x).
//      Search = fixed 9-step fully-unrolled select-only 8-chain batch
//      (8 independent LDS loads in flight per step; no divergent branches —
//      R4's failure was branchy guards + early-out). count = 6-shfl
//      butterfly; Illinois false-position pivot policy (R11, proven).
//      Waves 1-7 park at one release barrier.
//   3) endgame when T = C_hi-C_lo <= 512 (all threads, via windows dumped
//      to LDS): gather candidates, one bitonic sort, pick rank want1-C_lo.
//   median(squared diffs) = Dk*Dk (x -> fl(x^2) monotone on non-neg floats)
// ---------------------------------------------------------------------------
__global__ void __launch_bounds__(512)
median_bw_kernel(const float* __restrict__ particles, float* __restrict__ inv_bw)
{
    const int d = blockIdx.x, tid = threadIdx.x, lane = tid & 63, wid = tid >> 6;

    __shared__ float v[NP];
    __shared__ float cand[NP];
    __shared__ int   A_lds[NP];
    __shared__ int   B_lds[NP];
    __shared__ float sum_s[8];
    __shared__ int   scan_s[8];
    __shared__ int   done_s, T_s, rr_s;

    float r = particles[tid * DD + d];
    r = bitonic512(r, tid, v);
    __syncthreads();          // WAR vs last cross-stage reads inside sort
    v[tid] = r;
    __syncthreads();          // sorted array visible to all

    const float vj = r;       // sorted value owned by this thread (j = tid)
    const int want1 = (NPAIRS - 1) / 2 + 1;   // 65408 (1-based rank)

    // ---- pivot 0: mean of the 362 offset-150 diffs (block-wide) ----
    float s = (tid >= 150) ? (vj - v[tid - 150]) : 0.0f;
    #pragma unroll
    for (int off = 32; off > 0; off >>= 1) s += __shfl_xor(s, off);
    if (lane == 0) sum_s[wid] = s;
    __syncthreads();
    float msum = 0.0f;
    #pragma unroll
    for (int w = 0; w < 8; ++w) msum += sum_s[w];
    const float meanp = fmaxf(msum / 362.0f, 0.0f);   // uniform across block

    // ================= single-wave Illinois rounds =================
    if (wid == 0) {
        float vjw[8];
        int   wa[8], wb[8];
        #pragma unroll
        for (int w = 0; w < 8; ++w) {
            const int j = lane + 64 * w;
            vjw[w] = v[j];
            wa[w]  = 0;
            wb[w]  = j;       // window invariant: wa <= L_j <= wb
        }

        const float maxd = v[NP - 1] - v[0];
        unsigned lo = 0u;
        unsigned hi = __float_as_uint(maxd) + 1u;  // answer bits in [lo, hi]
        int C_lo = 0, C_hi = NPAIRS;
        int round = 0, last = 0;
        float g_lo = 0.5f - (float)want1;
        float g_hi = (float)(NPAIRS - want1) + 0.5f;

        while (lo < hi) {
            if (C_hi - C_lo <= NP) break;    // endgame

            const unsigned span = hi - lo;
            unsigned mid;
            if (round == 0) {
                mid = __float_as_uint(meanp);
            } else if ((round & 3) == 3) {   // hard safeguard: bit midpoint
                mid = lo + (span >> 1);
            } else {                         // Illinois secant, value space
                const float flo = __uint_as_float(lo);
                const float fhi = __uint_as_float(hi);
                const float xn  = (flo * g_hi - fhi * g_lo) / (g_hi - g_lo);
                mid = __float_as_uint(xn);
            }
            const unsigned dlt = span >> 3;  // force interior progress
            if (mid < lo + dlt)      mid = lo + dlt;
            if (mid > hi - 1u - dlt) mid = (hi - 1u) - dlt;
            if (mid < lo)            mid = lo;
            if (mid > hi - 1u)       mid = hi - 1u;
            const float x = __uint_as_float(mid);

            // 8 chains x fixed 9 select-only steps (window <= 511 -> done)
            int a0 = wa[0], b0 = wb[0], a1 = wa[1], b1 = wb[1];
            int a2 = wa[2], b2 = wb[2], a3 = wa[3], b3 = wb[3];
            int a4 = wa[4], b4 = wb[4], a5 = wa[5], b5 = wb[5];
            int a6 = wa[6], b6 = wb[6], a7 = wa[7], b7 = wb[7];
            #pragma unroll
            for (int step = 0; step < 9; ++step) {
                const int m0 = (a0 + b0) >> 1, m1 = (a1 + b1) >> 1;
                const int m2 = (a2 + b2) >> 1, m3 = (a3 + b3) >> 1;
                const int m4 = (a4 + b4) >> 1, m5 = (a5 + b5) >> 1;
                const int m6 = (a6 + b6) >> 1, m7 = (a7 + b7) >> 1;
                const float p0 = v[m0], p1 = v[m1], p2 = v[m2], p3 = v[m3];
                const float p4 = v[m4], p5 = v[m5], p6 = v[m6], p7 = v[m7];
                const bool g0 = a0 < b0, g1 = a1 < b1, g2 = a2 < b2, g3 = a3 < b3;
                const bool g4 = a4 < b4, g5 = a5 < b5, g6 = a6 < b6, g7 = a7 < b7;
                const bool t0 = vjw[0] - p0 <= x, t1 = vjw[1] - p1 <= x;
                const bool t2 = vjw[2] - p2 <= x, t3 = vjw[3] - p3 <= x;
                const bool t4 = vjw[4] - p4 <= x, t5 = vjw[5] - p5 <= x;
                const bool t6 = vjw[6] - p6 <= x, t7 = vjw[7] - p7 <= x;
                b0 = (g0 &  t0) ? m0 : b0;  a0 = (g0 & !t0) ? m0 + 1 : a0;
                b1 = (g1 &  t1) ? m1 : b1;  a1 = (g1 & !t1) ? m1 + 1 : a1;
                b2 = (g2 &  t2) ? m2 : b2;  a2 = (g2 & !t2) ? m2 + 1 : a2;
                b3 = (g3 &  t3) ? m3 : b3;  a3 = (g3 & !t3) ? m3 + 1 : a3;
                b4 = (g4 &  t4) ? m4 : b4;  a4 = (g4 & !t4) ? m4 + 1 : a4;
                b5 = (g5 &  t5) ? m5 : b5;  a5 = (g5 & !t5) ? m5 + 1 : a5;
                b6 = (g6 &  t6) ? m6 : b6;  a6 = (g6 & !t6) ? m6 + 1 : a6;
                b7 = (g7 &  t7) ? m7 : b7;  a7 = (g7 & !t7) ? m7 + 1 : a7;
            }

            int cnt = (lane + 0)   - a0;
            cnt    += (lane + 64)  - a1;
            cnt    += (lane + 128) - a2;
            cnt    += (lane + 192) - a3;
            cnt    += (lane + 256) - a4;
            cnt    += (lane + 320) - a5;
            cnt    += (lane + 384) - a6;
            cnt    += (lane + 448) - a7;
            #pragma unroll
            for (int off = 1; off < 64; off <<= 1)
                cnt += __shfl_xor(cnt, off);
            const int tot = cnt;                    // uniform across wave

            if (tot >= want1) {
                hi = mid; C_hi = tot;
                wa[0]=a0; wa[1]=a1; wa[2]=a2; wa[3]=a3;
                wa[4]=a4; wa[5]=a5; wa[6]=a6; wa[7]=a7;
                g_hi = (float)(tot - want1) + 0.5f;
                if (last == 1) g_lo *= 0.5f;        // Illinois
                last = 1;
            } else {
                lo = mid + 1u; C_lo = tot;
                wb[0]=a0; wb[1]=a1; wb[2]=a2; wb[3]=a3;
                wb[4]=a4; wb[5]=a5; wb[6]=a6; wb[7]=a7;
                g_lo = (float)(tot - want1) + 0.5f;
                if (last == -1) g_hi *= 0.5f;
                last = -1;
            }
            ++round;
        }

        if (lo >= hi) {
            if (lane == 0) {
                const float Dk = __uint_as_float(lo);
                const float h  = (Dk * Dk) / 6.240275844172107f;  // ln(513)
                inv_bw[d] = 1.0f / fmaxf(h, 1e-9f);
                done_s = 1;
            }
        } else {
            #pragma unroll
            for (int w = 0; w < 8; ++w) {
                A_lds[lane + 64 * w] = wa[w];
                B_lds[lane + 64 * w] = wb[w];
            }
            if (lane == 0) {
                done_s = 0;
                T_s    = C_hi - C_lo;
                rr_s   = min(want1 - C_lo, C_hi - C_lo);
            }
        }
    }
    __syncthreads();          // release parked waves; publish LDS state
    if (done_s) return;       // uniform

    // ---- endgame: T (<=512) candidates, rank rr within them ----
    const int T  = T_s;
    const int rr = rr_s;
    const int A  = A_lds[tid], B = B_lds[tid];
    const int n  = B - A;
    int inc = n;              // wave inclusive scan
    #pragma unroll
    for (int off = 1; off < 64; off <<= 1) {
        const int t = __shfl_up(inc, off);
        if (lane >= off) inc += t;
    }
    if (lane == 63) scan_s[wid] = inc;
    __syncthreads();
    int woff = 0;
    #pragma unroll
    for (int w = 0; w < 8; ++w) woff += (w < wid) ? scan_s[w] : 0;
    int off0 = woff + inc - n;            // exclusive global offset
    for (int i = A; i < B; ++i) cand[off0++] = vj - v[i];
    __syncthreads();

    float c = (tid < T) ? cand[tid] : INFINITY;
    c = bitonic512(c, tid, v);            // v reusable as scratch now

    if (tid == rr - 1) {
        const float Dk = c;
        const float h  = (Dk * Dk) / 6.240275844172107f;  // ln(513)
        inv_bw[d] = 1.0f / fmaxf(h, 1e-9f);
    }
}

// ---------------------------------------------------------------------------
// Kernel 2: write log_kernel and grad_log_kernel, float4-vectorized,
// PLAIN stores (nontemporal stores regressed write BW ~2.4x in R4).
// Flat float4 index t over (i, j, d4):  d4 = t & 31, j = (t>>5)&511, i = t>>14
// ---------------------------------------------------------------------------
__global__ void __launch_bounds__(256)
stein_out_kernel(const float* __restrict__ particles,
                 const float* __restrict__ inv_bw,
                 float4* __restrict__ out_lk,
                 float4* __restrict__ out_g)
{
    const float4* __restrict__ p4  = (const float4*)particles;
    const float4* __restrict__ ib4 = (const float4*)inv_bw;
    const int total = NP * NP * (DD / 4);   // 8,388,608

    for (int t = blockIdx.x * blockDim.x + threadIdx.x; t < total;
         t += gridDim.x * blockDim.x) {
        const int d4 = t & (DD / 4 - 1);        // 0..31
        const int j  = (t >> 5) & (NP - 1);     // 0..511
        const int i  = t >> 14;                 // 0..511

        const float4 xj = p4[j * (DD / 4) + d4];
        const float4 xi = p4[i * (DD / 4) + d4];
        const float4 ib = ib4[d4];

        float4 lk, g;
        {
            const float dx = xj.x - xi.x;
            lk.x = -(dx * dx * ib.x);
            g.x  = -2.0f * dx * ib.x;
        }
        {
            const float dx = xj.y - xi.y;
            lk.y = -(dx * dx * ib.y);
            g.y  = -2.0f * dx * ib.y;
        }
        {
            const float dx = xj.z - xi.z;
            lk.z = -(dx * dx * ib.z);
            g.z  = -2.0f * dx * ib.z;
        }
        {
            const float dx = xj.w - xi.w;
            lk.w = -(dx * dx * ib.w);
            g.w  = -2.0f * dx * ib.w;
        }
        out_lk[t] = lk;
        out_g[t]  = g;
    }
}

extern "C" void kernel_launch(void* const* d_in, const int* in_sizes, int n_in,
                              void* d_out, int out_size, void* d_ws, size_t ws_size,
                              hipStream_t stream)
{
    const float* particles = (const float*)d_in[0];
    float* out    = (float*)d_out;
    float* inv_bw = (float*)d_ws;   // 128 floats of scratch

    median_bw_kernel<<<DD, 512, 0, stream>>>(particles, inv_bw);

    float4* out_lk = (float4*)out;
    float4* out_g  = (float4*)(out + (size_t)NP * NP * DD);
    stein_out_kernel<<<2048, 256, 0, stream>>>(particles, inv_bw, out_lk, out_g);
}

// Round 13
// 64.358 us; speedup vs baseline: 1.3241x; 1.3241x over previous
//
#include <hip/hip_runtime.h>
#include <hip/hip_bf16.h>

#define NP 512                     // particles
#define DD 128                     // dims
#define NPAIRS (NP * (NP - 1) / 2) // 130816

// Hybrid bitonic sort of 512 floats (ascending): value in register r, one per
// thread; __shfl_xor for partner distance < 64, LDS exchange for s >= 64.
__device__ __forceinline__ float bitonic512(float r, int tid, float* lds)
{
    for (int k = 2; k <= NP; k <<= 1) {
        for (int s = k >> 1; s > 0; s >>= 1) {
            float other;
            if (s < 64) {
                other = __shfl_xor(r, s);
            } else {
                __syncthreads();
                lds[tid] = r;
                __syncthreads();
                other = lds[tid ^ s];
            }
            const bool lower = (tid & s) == 0;
            const bool up    = (tid & k) == 0;
            r = (lower == up) ? fminf(r, other) : fmaxf(r, other);
        }
    }
    return r;
}

// ---------------------------------------------------------------------------
// Kernel 1: per-dimension exact median of upper-triangular pairwise squared
// differences. One block (512 threads) per dimension d.
//   1) bitonic sort -> v[] (LDS); thread owns j = tid, vj = v[j]
//   2) verified-pivot rounds, SEEDED RANK-BISECTION policy:
//      rounds 0/1 seed a tight bracket at 0.93x / 1.07x the band-150 mean
//      (band mean ~ the answer; a miss merely degrades to plain bisection
//      since every pivot is VERIFIED by an exact count). Rounds >= 2 use the
//      VALUE-space midpoint (flo+fhi)/2: inside the seeded bracket the diff
//      density is near-uniform, so T = C_hi - C_lo halves per round
//      (Illinois chased the rank residual of ONE side; the endgame needs
//      BOTH sides tight -> it burned ~2 rounds per halving of T).
//      count via per-j warm windows [A,B] + select-only binary search
//      (proven primitive). 1 barrier per round.
//   3) endgame when T <= 512: gather candidates (prefix-sum offsets), one
//      bitonic sort, answer = rank (want1 - C_lo).
//   median(squared diffs) = Dk*Dk (x -> fl(x^2) monotone on non-neg floats)
// ---------------------------------------------------------------------------
__global__ void __launch_bounds__(512)
median_bw_kernel(const float* __restrict__ particles, float* __restrict__ inv_bw)
{
    const int d = blockIdx.x, tid = threadIdx.x, lane = tid & 63, wid = tid >> 6;

    __shared__ float v[NP];
    __shared__ float cand[NP];
    __shared__ int   cnt_s[2][8];
    __shared__ float sum_s[8];
    __shared__ int   scan_s[8];

    float r = particles[tid * DD + d];
    r = bitonic512(r, tid, v);
    __syncthreads();          // WAR vs last cross-stage reads inside sort
    v[tid] = r;
    __syncthreads();          // sorted array visible to all

    const float vj = r;       // sorted value owned by this thread (j = tid)
    const int want1 = (NPAIRS - 1) / 2 + 1;   // 65408 (1-based rank)

    // ---- band-150 mean: the rank-65408 pair sits at sorted offset ~150 ----
    float s = (tid >= 150) ? (vj - v[tid - 150]) : 0.0f;
    #pragma unroll
    for (int off = 32; off > 0; off >>= 1) s += __shfl_xor(s, off);
    if (lane == 0) sum_s[wid] = s;
    __syncthreads();
    float msum = 0.0f;
    #pragma unroll
    for (int w = 0; w < 8; ++w) msum += sum_s[w];
    const float meanp = fmaxf(msum / 362.0f, 0.0f);   // uniform across block

    const float maxd = v[NP - 1] - v[0];
    unsigned lo = 0u;
    unsigned hi = __float_as_uint(maxd) + 1u;   // answer bits in [lo, hi]
    int C_lo = 0;                   // count at pred(lo)   (< want1)
    int C_hi = NPAIRS;              // count at hi         (>= want1)
    int A = 0, B = tid;             // warm window: A <= L_j(x) <= B, x in [lo,hi]
    int buf = 0, round = 0;

    while (lo < hi) {
        if (C_hi - C_lo <= NP) break;    // endgame

        unsigned mid;
        if (round == 0) {
            mid = __float_as_uint(0.93f * meanp);   // seed: low side
        } else if (round == 1) {
            mid = __float_as_uint(1.07f * meanp);   // seed: high side
        } else {                                    // value-space midpoint
            const float flo = __uint_as_float(lo);
            const float fhi = __uint_as_float(hi);
            mid = __float_as_uint(0.5f * (flo + fhi));
        }
        if (mid < lo)      mid = lo;
        if (mid > hi - 1u) mid = hi - 1u;
        const float x = __uint_as_float(mid);

        // warm-started select-only lower_bound in [A,B] (proven primitive)
        int a = A, b = B;
        while (a < b) {
            const int   m  = (a + b) >> 1;
            const float pv = v[m];
            const bool  t  = (vj - pv <= x);
            b = t ? m : b;
            a = t ? a : m + 1;
        }
        int cnt = tid - a;               // #{i<j : fl(vj-vi) <= x}

        #pragma unroll
        for (int off = 32; off > 0; off >>= 1) cnt += __shfl_xor(cnt, off);
        if (lane == 0) cnt_s[buf][wid] = cnt;
        __syncthreads();                 // the ONLY barrier in the round
        int tot = 0;
        #pragma unroll
        for (int w = 0; w < 8; ++w) tot += cnt_s[buf][w];

        if (tot >= want1) { hi = mid;      C_hi = tot; A = a; }
        else              { lo = mid + 1u; C_lo = tot; B = a; }
        buf ^= 1;
        ++round;
    }

    if (lo >= hi) {
        // bracket collapsed to a single bit pattern: that's the answer
        if (tid == 0) {
            const float Dk = __uint_as_float(lo);
            const float h  = (Dk * Dk) / 6.240275844172107f;  // ln(513)
            inv_bw[d] = 1.0f / fmaxf(h, 1e-9f);
        }
    } else {
        // ---- endgame: T (<=512) candidates, rank rr within them ----
        const int T  = C_hi - C_lo;
        const int rr = min(want1 - C_lo, T);  // 1-based, 1 <= rr <= T
        const int n  = B - A;                 // this thread's candidates
        int inc = n;                          // wave inclusive scan
        #pragma unroll
        for (int off = 1; off < 64; off <<= 1) {
            const int t = __shfl_up(inc, off);
            if (lane >= off) inc += t;
        }
        if (lane == 63) scan_s[wid] = inc;
        __syncthreads();
        int woff = 0;
        #pragma unroll
        for (int w = 0; w < 8; ++w) woff += (w < wid) ? scan_s[w] : 0;
        int off0 = woff + inc - n;            // exclusive global offset
        for (int i = A; i < B; ++i) cand[off0++] = vj - v[i];
        __syncthreads();

        float c = (tid < T) ? cand[tid] : INFINITY;
        c = bitonic512(c, tid, v);            // v reusable as scratch now

        if (tid == rr - 1) {
            const float Dk = c;
            const float h  = (Dk * Dk) / 6.240275844172107f;  // ln(513)
            inv_bw[d] = 1.0f / fmaxf(h, 1e-9f);
        }
    }
}

// ---------------------------------------------------------------------------
// Kernel 2: write log_kernel and grad_log_kernel, float4-vectorized,
// PLAIN stores (nontemporal stores regressed write BW ~2.4x in R4).
// Flat float4 index t over (i, j, d4):  d4 = t & 31, j = (t>>5)&511, i = t>>14
// ---------------------------------------------------------------------------
__global__ void __launch_bounds__(256)
stein_out_kernel(const float* __restrict__ particles,
                 const float* __restrict__ inv_bw,
                 float4* __restrict__ out_lk,
                 float4* __restrict__ out_g)
{
    const float4* __restrict__ p4  = (const float4*)particles;
    const float4* __restrict__ ib4 = (const float4*)inv_bw;
    const int total = NP * NP * (DD / 4);   // 8,388,608

    for (int t = blockIdx.x * blockDim.x + threadIdx.x; t < total;
         t += gridDim.x * blockDim.x) {
        const int d4 = t & (DD / 4 - 1);        // 0..31
        const int j  = (t >> 5) & (NP - 1);     // 0..511
        const int i  = t >> 14;                 // 0..511

        const float4 xj = p4[j * (DD / 4) + d4];
        const float4 xi = p4[i * (DD / 4) + d4];
        const float4 ib = ib4[d4];

        float4 lk, g;
        {
            const float dx = xj.x - xi.x;
            lk.x = -(dx * dx * ib.x);
            g.x  = -2.0f * dx * ib.x;
        }
        {
            const float dx = xj.y - xi.y;
            lk.y = -(dx * dx * ib.y);
            g.y  = -2.0f * dx * ib.y;
        }
        {
            const float dx = xj.z - xi.z;
            lk.z = -(dx * dx * ib.z);
            g.z  = -2.0f * dx * ib.z;
        }
        {
            const float dx = xj.w - xi.w;
            lk.w = -(dx * dx * ib.w);
            g.w  = -2.0f * dx * ib.w;
        }
        out_lk[t] = lk;
        out_g[t]  = g;
    }
}

extern "C" void kernel_launch(void* const* d_in, const int* in_sizes, int n_in,
                              void* d_out, int out_size, void* d_ws, size_t ws_size,
                              hipStream_t stream)
{
    const float* particles = (const float*)d_in[0];
    float* out    = (float*)d_out;
    float* inv_bw = (float*)d_ws;   // 128 floats of scratch

    median_bw_kernel<<<DD, 512, 0, stream>>>(particles, inv_bw);

    float4* out_lk = (float4*)out;
    float4* out_g  = (float4*)(out + (size_t)NP * NP * DD);
    stein_out_kernel<<<2048, 256, 0, stream>>>(particles, inv_bw, out_lk, out_g);
}